// Round 2
// baseline (117320.300 us; speedup 1.0000x reference)
//
#include <hip/hip_runtime.h>

// Problem: B=16, S=1024, C=509 -> IN=512, H=600, bidirectional GRU, one serial
// hidden state over all 16384 steps per direction.
//
// Pipeline: detect dtype -> embed/concat X (bf16) -> cast W_ih to bf16 ->
// MFMA GEMM gx = X@W_ih^T + b_ih (fp16 out, 59MB) -> persistent 150-WG
// recurrence with device-scope flag barrier per step.
//
// Workspace layout (total ~74.0 MiB; previous round's 128.5 MiB likely
// overflowed ws -> flags/gx-tail in foreign memory -> NaN):
//   X  @ 0           : 16384*512*2  = 16,777,216
//   GX @ 16,777,216  : 16384*1800*2 = 58,982,400 (fp16)   end 75,759,616
//   HB @ 75,759,616  : 16,384 pad region (h double buffers, fp32)
//   FL @ 75,776,000  : 19,200 (150 flag cachelines)
//   DF @ 75,795,200  : 256 (dtype flag)
//   WB @ 75,795,456  : 1800*512*2 = 1,843,200 (W_ih as bf16) end 77,638,656

#define HDIM   600
#define TH3    1800
#define NROWS  16384
#define KDIM   512
#define NW     75
#define EPW    8
#define NSTEP  16384
#define CH     76
#define HPAD   608

#define OFF_GX 16777216ull
#define OFF_HB 75759616ull
#define OFF_FL 75776000ull
#define OFF_DF 75795200ull
#define OFF_WB 75795456ull

typedef short bf16x8 __attribute__((ext_vector_type(8)));
typedef float f32x4  __attribute__((ext_vector_type(4)));
typedef _Float16 f16;

__device__ __forceinline__ float bf2f(unsigned short u) {
  union { unsigned u32; float f; } v; v.u32 = ((unsigned)u) << 16; return v.f;
}
__device__ __forceinline__ unsigned short f2bf(float f) {
  union { float f; unsigned u; } v; v.f = f;
  unsigned r = (v.u + 0x7FFFu + ((v.u >> 16) & 1u)) >> 16;   // RNE
  return (unsigned short)r;
}

// ---- init: zero h buffers + flags; detect input dtype (bf16 vs fp32) ------
// True-bf16 normal samples have exponent field in ~[0x68,0x87]; if the buffer
// is really fp32, even-index u16s are f32 low-mantissa bits -> their "exponent
// field" is uniform -> hits <0x10 or >=0xF0 w.p. 1/8 per sample.
__global__ void init_k(const unsigned short* __restrict__ ctx,
                       float* __restrict__ hb, int* __restrict__ fl,
                       int* __restrict__ df) {
  int i = blockIdx.x * 256 + threadIdx.x;
  if (i < 2 * 2 * HPAD) hb[i] = 0.f;
  if (i < 2 * NW * 32) fl[i] = 0;
  if (blockIdx.x == 0 && threadIdx.x == 0) {
    int bad = 0;
    for (int k = 0; k < 512; ++k) {
      unsigned e = (ctx[2 * k] >> 7) & 0xFFu;
      bad += (e >= 0xF0u) | (e < 0x10u);
    }
    df[0] = (bad > 0) ? 1 : 0;
  }
}

// ---- embed + concat -> X bf16 [16384][512] --------------------------------
__global__ void embed_k(const unsigned short* __restrict__ ctx,
                        const int* __restrict__ tags,
                        const unsigned short* __restrict__ temb,
                        unsigned short* __restrict__ x,
                        const int* __restrict__ df) {
  const int fp32 = df[0];
  int idx = blockIdx.x * 256 + threadIdx.x;
  int row = idx >> 9, j = idx & 511;
  unsigned short v;
  if (fp32) {
    const float* ctxF  = (const float*)ctx;
    const float* tembF = (const float*)temb;
    v = (j < 3) ? f2bf(tembF[tags[row] * 3 + j]) : f2bf(ctxF[row * 509 + (j - 3)]);
  } else {
    v = (j < 3) ? temb[tags[row] * 3 + j] : ctx[row * 509 + (j - 3)];
  }
  x[idx] = v;
}

// ---- W_ih -> bf16 copy (no-op copy in bf16 mode) --------------------------
__global__ void wcast_k(const unsigned short* __restrict__ wih,
                        unsigned short* __restrict__ wb,
                        const int* __restrict__ df) {
  const int fp32 = df[0];
  int i = blockIdx.x * 256 + threadIdx.x;            // 1800*512 total
  wb[i] = fp32 ? f2bf(((const float*)wih)[i]) : wih[i];
}

// ---- GEMM: gx[16384][1800] = X @ W_ih^T + b_ih (fp16 out) -----------------
__global__ __launch_bounds__(256) void gemm_k(const unsigned short* __restrict__ X,
                                              const unsigned short* __restrict__ Wb,
                                              const unsigned short* __restrict__ bih,
                                              f16* __restrict__ gx,
                                              const int* __restrict__ df) {
  const int fp32 = df[0];
  const int lane = threadIdx.x & 63;
  const int wv   = threadIdx.x >> 6;
  const int mt   = blockIdx.y * 4 + wv;              // 0..1023
  const int nt   = blockIdx.x;                       // 0..112
  const int mrow = mt * 16 + (lane & 15);
  const int ncol = nt * 16 + (lane & 15);
  const int koff = (lane >> 4) * 8;                  // A[m][k=quad*8+j]
  const int nclamp = (ncol < TH3) ? ncol : (TH3 - 1);

  const bf16x8* ap = (const bf16x8*)(X  + (size_t)mrow   * KDIM + koff);
  const bf16x8* bp = (const bf16x8*)(Wb + (size_t)nclamp * KDIM + koff);

  f32x4 acc = {0.f, 0.f, 0.f, 0.f};
  #pragma unroll
  for (int kc = 0; kc < 16; ++kc) {
    bf16x8 av = ap[kc * 4];
    bf16x8 bv = bp[kc * 4];
    acc = __builtin_amdgcn_mfma_f32_16x16x32_bf16(av, bv, acc, 0, 0, 0);
  }
  if (ncol < TH3) {
    const float bias = fp32 ? ((const float*)bih)[ncol] : bf2f(bih[ncol]);
    const int r0 = mt * 16 + (lane >> 4) * 4;        // C/D: col=lane&15, row=quad*4+reg
    #pragma unroll
    for (int i = 0; i < 4; ++i)
      gx[(size_t)(r0 + i) * TH3 + ncol] = (f16)(acc[i] + bias);
  }
}

// ---- persistent bidirectional GRU recurrence ------------------------------
// 150 WGs (d = bid&1, w = bid>>1). WG owns h[8w..8w+8) of its direction.
// W_hh slice (24 rows x 600, fp32) in VGPRs. Monotonic per-WG flags +
// parity double-buffered h; max step skew is 1 by the flag wait.
__global__ __launch_bounds__(256, 1) void gru_rec(const unsigned short* __restrict__ Whh,
                                                  const unsigned short* __restrict__ bhh,
                                                  const f16* __restrict__ gx,
                                                  float* __restrict__ hbuf,   // [2][2][HPAD]
                                                  int* __restrict__ flags,    // [150]*32
                                                  void* __restrict__ outv,
                                                  const int* __restrict__ df) {
  const int fp32 = df[0];
  const int tid = threadIdx.x;
  const int d   = blockIdx.x & 1;
  const int w   = blockIdx.x >> 1;

  __shared__ __align__(16) float hlds[HPAD];
  __shared__ float ghl[24];

  if (tid < HPAD - HDIM) hlds[HDIM + tid] = 0.f;

  const int r = tid >> 3;            // 0..31 (24 used)
  const int c = tid & 7;
  const bool dot_t = (tid < 192);
  f32x4 wvr[19];
  if (dot_t) {
    const int g = r >> 3, e = r & 7;
    const int row = g * HDIM + w * EPW + e;
    if (fp32) {
      const float* wp = ((const float*)Whh) + (size_t)row * HDIM + c * CH;
      #pragma unroll
      for (int q = 0; q < 19; ++q) {
        const int kb = c * CH + q * 4;
        f32x4 v;
        if (kb + 3 < HDIM) {
          v = *(const f32x4*)(wp + q * 4);
        } else {
          #pragma unroll
          for (int j = 0; j < 4; ++j)
            v[j] = (kb + j < HDIM) ? wp[q * 4 + j] : 0.f;
        }
        wvr[q] = v;
      }
    } else {
      const unsigned short* wp = Whh + (size_t)row * HDIM + c * CH;
      #pragma unroll
      for (int q = 0; q < 19; ++q) {
        const int kb = c * CH + q * 4;
        f32x4 v;
        if (kb + 3 < HDIM) {
          ushort4 u = *(const ushort4*)(wp + q * 4);
          v[0] = bf2f(u.x); v[1] = bf2f(u.y); v[2] = bf2f(u.z); v[3] = bf2f(u.w);
        } else {
          #pragma unroll
          for (int j = 0; j < 4; ++j)
            v[j] = (kb + j < HDIM) ? bf2f(wp[q * 4 + j]) : 0.f;
        }
        wvr[q] = v;
      }
    }
  }

  float bhr = 0.f, bhz = 0.f, bhn = 0.f;
  if (tid < EPW) {
    const int i = w * EPW + tid;
    if (fp32) {
      const float* bF = (const float*)bhh;
      bhr = bF[i]; bhz = bF[HDIM + i]; bhn = bF[2 * HDIM + i];
    } else {
      bhr = bf2f(bhh[i]); bhz = bf2f(bhh[HDIM + i]); bhn = bf2f(bhh[2 * HDIM + i]);
    }
  }
  const int fidx = (d * NW + w) * 32;

  for (int t = 0; t < NSTEP; ++t) {
    // prefetch this step's gx (independent of h)
    float gxr = 0.f, gxz = 0.f, gxn = 0.f;
    if (tid < EPW) {
      const int rw = (d == 0) ? t : (((t >> 10) << 10) + (1023 - (t & 1023)));
      const f16* p = gx + (size_t)rw * TH3 + w * EPW + tid;
      gxr = (float)p[0]; gxz = (float)p[HDIM]; gxn = (float)p[2 * HDIM];
    }
    // wait for all WGs of this direction to publish h_t
    if (tid < NW) {
      const int* fp = flags + (d * NW + tid) * 32;
      while (__hip_atomic_load(fp, __ATOMIC_ACQUIRE, __HIP_MEMORY_SCOPE_AGENT) < t)
        __builtin_amdgcn_s_sleep(1);
    }
    __syncthreads();
    // stage h_t into LDS
    {
      const float* hsrc = hbuf + ((t & 1) * 2 + d) * HPAD;
      for (int k = tid; k < HDIM; k += 256)
        hlds[k] = __hip_atomic_load(hsrc + k, __ATOMIC_RELAXED, __HIP_MEMORY_SCOPE_AGENT);
    }
    __syncthreads();
    float hold = 0.f;
    if (tid < EPW) hold = hlds[w * EPW + tid];
    // 24 row-dots of length 600 (W in regs, h in LDS, 8-way broadcast)
    if (dot_t) {
      float acc = 0.f;
      const float* hp = hlds + c * CH;
      #pragma unroll
      for (int q = 0; q < 19; ++q) {
        f32x4 h4 = *(const f32x4*)(hp + 4 * q);
        acc += wvr[q][0] * h4[0] + wvr[q][1] * h4[1]
             + wvr[q][2] * h4[2] + wvr[q][3] * h4[3];
      }
      acc += __shfl_xor(acc, 1);
      acc += __shfl_xor(acc, 2);
      acc += __shfl_xor(acc, 4);
      if (c == 0) ghl[r] = acc;
    }
    __syncthreads();
    // gates + state update (fp32), publish h_{t+1}
    if (tid < EPW) {
      const float rr  = 1.f / (1.f + __expf(-(gxr + ghl[tid] + bhr)));
      const float zz  = 1.f / (1.f + __expf(-(gxz + ghl[8 + tid] + bhz)));
      const float pre = gxn + rr * (ghl[16 + tid] + bhn);
      const float nn  = 1.f - 2.f / (1.f + __expf(2.f * pre));   // tanh(pre)
      const float hn  = nn + zz * (hold - nn);
      float* hdst = hbuf + (((t + 1) & 1) * 2 + d) * HPAD + w * EPW + tid;
      __hip_atomic_store(hdst, hn, __ATOMIC_RELAXED, __HIP_MEMORY_SCOPE_AGENT);
      if (t == NSTEP - 1) {
        const int o = d * HDIM + w * EPW + tid;
        if (fp32) ((float*)outv)[o] = hn;
        else      ((unsigned short*)outv)[o] = f2bf(hn);
      }
    }
    __syncthreads();   // drains vmcnt: h stores globally issued before flag
    if (tid == 0)
      __hip_atomic_store(flags + fidx, t + 1, __ATOMIC_RELEASE, __HIP_MEMORY_SCOPE_AGENT);
  }
}

extern "C" void kernel_launch(void* const* d_in, const int* in_sizes, int n_in,
                              void* d_out, int out_size, void* d_ws, size_t ws_size,
                              hipStream_t stream) {
  const unsigned short* ctx  = (const unsigned short*)d_in[0];
  const int*            tags = (const int*)d_in[1];
  const unsigned short* temb = (const unsigned short*)d_in[2];
  const unsigned short* wih  = (const unsigned short*)d_in[3];
  const unsigned short* whh  = (const unsigned short*)d_in[4];
  const unsigned short* bih  = (const unsigned short*)d_in[5];
  const unsigned short* bhh  = (const unsigned short*)d_in[6];

  char* ws = (char*)d_ws;
  unsigned short* X  = (unsigned short*)ws;
  f16*            GX = (f16*)(ws + OFF_GX);
  float*          HB = (float*)(ws + OFF_HB);
  int*            FL = (int*)  (ws + OFF_FL);
  int*            DF = (int*)  (ws + OFF_DF);
  unsigned short* WB = (unsigned short*)(ws + OFF_WB);

  init_k <<<32, 256, 0, stream>>>(ctx, HB, FL, DF);
  embed_k<<<(NROWS * KDIM) / 256, 256, 0, stream>>>(ctx, tags, temb, X, DF);
  wcast_k<<<(TH3 * KDIM) / 256, 256, 0, stream>>>(wih, WB, DF);
  gemm_k <<<dim3(113, 256), 256, 0, stream>>>(X, WB, bih, GX, DF);
  gru_rec<<<2 * NW, 256, 0, stream>>>(whh, bhh, GX, HB, FL, d_out, DF);
}

// Round 4
// 95634.302 us; speedup vs baseline: 1.2268x; 1.2268x over previous
//
#include <hip/hip_runtime.h>

// Problem: B=16, S=1024, C=509 -> IN=512, H=600, bidirectional GRU, one serial
// hidden state over all 16384 steps per direction.
//
// Pipeline: detect dtype -> embed/concat X (bf16) -> cast W_ih to bf16 ->
// MFMA GEMM gx = X@W_ih^T + b_ih (fp16 out, 59MB) -> persistent 150-WG
// recurrence with device-scope flag barrier per step.
//
// R3/R4 change: all spin-wait flag loads RELAXED (acquire polls emitted a
// buffer_inv per iteration), flag publish RELAXED after __syncthreads (its
// vmcnt(0) drain is the release; avoids buffer_wbl2 per step). One acquire
// fence per step after poll exit (__builtin_amdgcn_fence — __hip_atomic_fence
// does not exist in this ROCm).
//
// Workspace layout (total ~74.0 MiB):
//   X  @ 0           : 16384*512*2  = 16,777,216
//   GX @ 16,777,216  : 16384*1800*2 = 58,982,400 (fp16)   end 75,759,616
//   HB @ 75,759,616  : 16,384 pad region (h double buffers, fp32)
//   FL @ 75,776,000  : 19,200 (150 flag cachelines)
//   DF @ 75,795,200  : 256 (dtype flag)
//   WB @ 75,795,456  : 1800*512*2 = 1,843,200 (W_ih bf16)  end 77,638,656

#define HDIM   600
#define TH3    1800
#define NROWS  16384
#define KDIM   512
#define NW     75
#define EPW    8
#define NSTEP  16384
#define CH     76
#define HPAD   608

#define OFF_GX 16777216ull
#define OFF_HB 75759616ull
#define OFF_FL 75776000ull
#define OFF_DF 75795200ull
#define OFF_WB 75795456ull

typedef short bf16x8 __attribute__((ext_vector_type(8)));
typedef float f32x4  __attribute__((ext_vector_type(4)));
typedef _Float16 f16;

__device__ __forceinline__ float bf2f(unsigned short u) {
  union { unsigned u32; float f; } v; v.u32 = ((unsigned)u) << 16; return v.f;
}
__device__ __forceinline__ unsigned short f2bf(float f) {
  union { float f; unsigned u; } v; v.f = f;
  unsigned r = (v.u + 0x7FFFu + ((v.u >> 16) & 1u)) >> 16;   // RNE
  return (unsigned short)r;
}

// ---- init: zero h buffers + flags; detect input dtype (bf16 vs fp32) ------
__global__ void init_k(const unsigned short* __restrict__ ctx,
                       float* __restrict__ hb, int* __restrict__ fl,
                       int* __restrict__ df) {
  int i = blockIdx.x * 256 + threadIdx.x;
  if (i < 2 * 2 * HPAD) hb[i] = 0.f;
  if (i < 2 * NW * 32) fl[i] = 0;
  if (blockIdx.x == 0 && threadIdx.x == 0) {
    int bad = 0;
    for (int k = 0; k < 512; ++k) {
      unsigned e = (ctx[2 * k] >> 7) & 0xFFu;
      bad += (e >= 0xF0u) | (e < 0x10u);
    }
    df[0] = (bad > 0) ? 1 : 0;
  }
}

// ---- embed + concat -> X bf16 [16384][512] --------------------------------
__global__ void embed_k(const unsigned short* __restrict__ ctx,
                        const int* __restrict__ tags,
                        const unsigned short* __restrict__ temb,
                        unsigned short* __restrict__ x,
                        const int* __restrict__ df) {
  const int fp32 = df[0];
  int idx = blockIdx.x * 256 + threadIdx.x;
  int row = idx >> 9, j = idx & 511;
  unsigned short v;
  if (fp32) {
    const float* ctxF  = (const float*)ctx;
    const float* tembF = (const float*)temb;
    v = (j < 3) ? f2bf(tembF[tags[row] * 3 + j]) : f2bf(ctxF[row * 509 + (j - 3)]);
  } else {
    v = (j < 3) ? temb[tags[row] * 3 + j] : ctx[row * 509 + (j - 3)];
  }
  x[idx] = v;
}

// ---- W_ih -> bf16 copy (no-op copy in bf16 mode) --------------------------
__global__ void wcast_k(const unsigned short* __restrict__ wih,
                        unsigned short* __restrict__ wb,
                        const int* __restrict__ df) {
  const int fp32 = df[0];
  int i = blockIdx.x * 256 + threadIdx.x;            // 1800*512 total
  wb[i] = fp32 ? f2bf(((const float*)wih)[i]) : wih[i];
}

// ---- GEMM: gx[16384][1800] = X @ W_ih^T + b_ih (fp16 out) -----------------
__global__ __launch_bounds__(256) void gemm_k(const unsigned short* __restrict__ X,
                                              const unsigned short* __restrict__ Wb,
                                              const unsigned short* __restrict__ bih,
                                              f16* __restrict__ gx,
                                              const int* __restrict__ df) {
  const int fp32 = df[0];
  const int lane = threadIdx.x & 63;
  const int wv   = threadIdx.x >> 6;
  const int mt   = blockIdx.y * 4 + wv;              // 0..1023
  const int nt   = blockIdx.x;                       // 0..112
  const int mrow = mt * 16 + (lane & 15);
  const int ncol = nt * 16 + (lane & 15);
  const int koff = (lane >> 4) * 8;                  // A[m][k=quad*8+j]
  const int nclamp = (ncol < TH3) ? ncol : (TH3 - 1);

  const bf16x8* ap = (const bf16x8*)(X  + (size_t)mrow   * KDIM + koff);
  const bf16x8* bp = (const bf16x8*)(Wb + (size_t)nclamp * KDIM + koff);

  f32x4 acc = {0.f, 0.f, 0.f, 0.f};
  #pragma unroll
  for (int kc = 0; kc < 16; ++kc) {
    bf16x8 av = ap[kc * 4];
    bf16x8 bv = bp[kc * 4];
    acc = __builtin_amdgcn_mfma_f32_16x16x32_bf16(av, bv, acc, 0, 0, 0);
  }
  if (ncol < TH3) {
    const float bias = fp32 ? ((const float*)bih)[ncol] : bf2f(bih[ncol]);
    const int r0 = mt * 16 + (lane >> 4) * 4;        // C/D: col=lane&15, row=quad*4+reg
    #pragma unroll
    for (int i = 0; i < 4; ++i)
      gx[(size_t)(r0 + i) * TH3 + ncol] = (f16)(acc[i] + bias);
  }
}

// ---- persistent bidirectional GRU recurrence ------------------------------
// 150 WGs (d = bid&1, w = bid>>1). WG owns h[8w..8w+8) of its direction.
// W_hh slice (24 rows x 600, fp32) in VGPRs. Monotonic per-WG flags +
// parity double-buffered h; max step skew is 1 by the flag wait.
__global__ __launch_bounds__(256, 1) void gru_rec(const unsigned short* __restrict__ Whh,
                                                  const unsigned short* __restrict__ bhh,
                                                  const f16* __restrict__ gx,
                                                  float* __restrict__ hbuf,   // [2][2][HPAD]
                                                  int* __restrict__ flags,    // [150]*32
                                                  void* __restrict__ outv,
                                                  const int* __restrict__ df) {
  const int fp32 = df[0];
  const int tid = threadIdx.x;
  const int d   = blockIdx.x & 1;
  const int w   = blockIdx.x >> 1;

  __shared__ __align__(16) float hlds[HPAD];
  __shared__ float ghl[24];

  if (tid < HPAD - HDIM) hlds[HDIM + tid] = 0.f;

  const int r = tid >> 3;            // 0..31 (24 used)
  const int c = tid & 7;
  const bool dot_t = (tid < 192);
  f32x4 wvr[19];
  if (dot_t) {
    const int g = r >> 3, e = r & 7;
    const int row = g * HDIM + w * EPW + e;
    if (fp32) {
      const float* wp = ((const float*)Whh) + (size_t)row * HDIM + c * CH;
      #pragma unroll
      for (int q = 0; q < 19; ++q) {
        const int kb = c * CH + q * 4;
        f32x4 v;
        if (kb + 3 < HDIM) {
          v = *(const f32x4*)(wp + q * 4);
        } else {
          #pragma unroll
          for (int j = 0; j < 4; ++j)
            v[j] = (kb + j < HDIM) ? wp[q * 4 + j] : 0.f;
        }
        wvr[q] = v;
      }
    } else {
      const unsigned short* wp = Whh + (size_t)row * HDIM + c * CH;
      #pragma unroll
      for (int q = 0; q < 19; ++q) {
        const int kb = c * CH + q * 4;
        f32x4 v;
        if (kb + 3 < HDIM) {
          ushort4 u = *(const ushort4*)(wp + q * 4);
          v[0] = bf2f(u.x); v[1] = bf2f(u.y); v[2] = bf2f(u.z); v[3] = bf2f(u.w);
        } else {
          #pragma unroll
          for (int j = 0; j < 4; ++j)
            v[j] = (kb + j < HDIM) ? bf2f(wp[q * 4 + j]) : 0.f;
        }
        wvr[q] = v;
      }
    }
  }

  float bhr = 0.f, bhz = 0.f, bhn = 0.f;
  if (tid < EPW) {
    const int i = w * EPW + tid;
    if (fp32) {
      const float* bF = (const float*)bhh;
      bhr = bF[i]; bhz = bF[HDIM + i]; bhn = bF[2 * HDIM + i];
    } else {
      bhr = bf2f(bhh[i]); bhz = bf2f(bhh[HDIM + i]); bhn = bf2f(bhh[2 * HDIM + i]);
    }
  }
  const int fidx = (d * NW + w) * 32;

  for (int t = 0; t < NSTEP; ++t) {
    // prefetch this step's gx (independent of h; overlaps poll latency)
    float gxr = 0.f, gxz = 0.f, gxn = 0.f;
    if (tid < EPW) {
      const int rw = (d == 0) ? t : (((t >> 10) << 10) + (1023 - (t & 1023)));
      const f16* p = gx + (size_t)rw * TH3 + w * EPW + tid;
      gxr = (float)p[0]; gxz = (float)p[HDIM]; gxn = (float)p[2 * HDIM];
    }
    // wait for all WGs of this direction to publish h_t.
    // RELAXED polls: agent-scope atomics are uncached (sc1) so there is no
    // stale-cache hazard; acquire-per-iteration emitted buffer_inv each spin.
    if (tid < NW) {
      const int* fp = flags + (d * NW + tid) * 32;
      while (__hip_atomic_load(fp, __ATOMIC_RELAXED, __HIP_MEMORY_SCOPE_AGENT) < t)
        __builtin_amdgcn_s_sleep(2);
    }
    __builtin_amdgcn_fence(__ATOMIC_ACQUIRE, "agent");  // once/step
    __syncthreads();
    // stage h_t into LDS
    {
      const float* hsrc = hbuf + ((t & 1) * 2 + d) * HPAD;
      for (int k = tid; k < HDIM; k += 256)
        hlds[k] = __hip_atomic_load(hsrc + k, __ATOMIC_RELAXED, __HIP_MEMORY_SCOPE_AGENT);
    }
    __syncthreads();
    float hold = 0.f;
    if (tid < EPW) hold = hlds[w * EPW + tid];
    // 24 row-dots of length 600 (W in regs, h in LDS, 8-way broadcast)
    if (dot_t) {
      float acc = 0.f;
      const float* hp = hlds + c * CH;
      #pragma unroll
      for (int q = 0; q < 19; ++q) {
        f32x4 h4 = *(const f32x4*)(hp + 4 * q);
        acc += wvr[q][0] * h4[0] + wvr[q][1] * h4[1]
             + wvr[q][2] * h4[2] + wvr[q][3] * h4[3];
      }
      acc += __shfl_xor(acc, 1);
      acc += __shfl_xor(acc, 2);
      acc += __shfl_xor(acc, 4);
      if (c == 0) ghl[r] = acc;
    }
    __syncthreads();
    // gates + state update (fp32), publish h_{t+1}
    if (tid < EPW) {
      const float rr  = 1.f / (1.f + __expf(-(gxr + ghl[tid] + bhr)));
      const float zz  = 1.f / (1.f + __expf(-(gxz + ghl[8 + tid] + bhz)));
      const float pre = gxn + rr * (ghl[16 + tid] + bhn);
      const float nn  = 1.f - 2.f / (1.f + __expf(2.f * pre));   // tanh(pre)
      const float hn  = nn + zz * (hold - nn);
      float* hdst = hbuf + (((t + 1) & 1) * 2 + d) * HPAD + w * EPW + tid;
      __hip_atomic_store(hdst, hn, __ATOMIC_RELAXED, __HIP_MEMORY_SCOPE_AGENT);
      if (t == NSTEP - 1) {
        const int o = d * HDIM + w * EPW + tid;
        if (fp32) ((float*)outv)[o] = hn;
        else      ((unsigned short*)outv)[o] = f2bf(hn);
      }
    }
    // __syncthreads emits s_waitcnt vmcnt(0) before s_barrier: the h stores
    // (write-through sc1) are complete at the coherence point before any
    // thread proceeds -> relaxed flag store below is a valid release.
    __syncthreads();
    if (tid == 0)
      __hip_atomic_store(flags + fidx, t + 1, __ATOMIC_RELAXED, __HIP_MEMORY_SCOPE_AGENT);
  }
}

extern "C" void kernel_launch(void* const* d_in, const int* in_sizes, int n_in,
                              void* d_out, int out_size, void* d_ws, size_t ws_size,
                              hipStream_t stream) {
  const unsigned short* ctx  = (const unsigned short*)d_in[0];
  const int*            tags = (const int*)d_in[1];
  const unsigned short* temb = (const unsigned short*)d_in[2];
  const unsigned short* wih  = (const unsigned short*)d_in[3];
  const unsigned short* whh  = (const unsigned short*)d_in[4];
  const unsigned short* bih  = (const unsigned short*)d_in[5];
  const unsigned short* bhh  = (const unsigned short*)d_in[6];

  char* ws = (char*)d_ws;
  unsigned short* X  = (unsigned short*)ws;
  f16*            GX = (f16*)(ws + OFF_GX);
  float*          HB = (float*)(ws + OFF_HB);
  int*            FL = (int*)  (ws + OFF_FL);
  int*            DF = (int*)  (ws + OFF_DF);
  unsigned short* WB = (unsigned short*)(ws + OFF_WB);

  init_k <<<32, 256, 0, stream>>>(ctx, HB, FL, DF);
  embed_k<<<(NROWS * KDIM) / 256, 256, 0, stream>>>(ctx, tags, temb, X, DF);
  wcast_k<<<(TH3 * KDIM) / 256, 256, 0, stream>>>(wih, WB, DF);
  gemm_k <<<dim3(113, 256), 256, 0, stream>>>(X, WB, bih, GX, DF);
  gru_rec<<<2 * NW, 256, 0, stream>>>(whh, bhh, GX, HB, FL, d_out, DF);
}

// Round 5
// 37529.129 us; speedup vs baseline: 3.1261x; 2.5483x over previous
//
#include <hip/hip_runtime.h>

// Problem: B=16, S=1024, C=509 -> IN=512, H=600, bidirectional GRU, one serial
// hidden state over all 16384 steps per direction.
//
// R5 change (structural): fused data+flag publication. Each WG publishes its
// 8 h elements as 8-byte pairs {low dword = step counter, high dword = f32
// bits} via single 64-bit agent-scope atomic stores (parity double-buffered,
// monotonic counters -> per-pair self-validation, no torn/stale hazard).
// Readers poll the 150 lines directly into LDS. This removes the separate
// flag array, the h buffer, the pre-flag vmcnt(0) store-ack drain, and the
// separate h-load round trip: 3 global RTs + drain -> 1 visibility + 1 poll.
// Barriers per step: 4 -> 2.
//
// Workspace layout (total ~74.0 MiB):
//   X   @ 0           : 16384*512*2  = 16,777,216
//   GX  @ 16,777,216  : 16384*1800*2 = 58,982,400 (fp16)   end 75,759,616
//   PUB @ 75,776,000  : 2dir*2par*75wg*64B = 19,200 (h+counter pairs)
//   DF  @ 75,795,200  : 256 (dtype flag)
//   WB  @ 75,795,456  : 1800*512*2 = 1,843,200 (W_ih bf16)  end 77,638,656

#define HDIM   600
#define TH3    1800
#define NROWS  16384
#define KDIM   512
#define NW     75
#define EPW    8
#define NSTEP  16384
#define CH     76
#define HPAD   608

#define OFF_GX 16777216ull
#define OFF_PB 75776000ull
#define OFF_DF 75795200ull
#define OFF_WB 75795456ull

typedef short bf16x8 __attribute__((ext_vector_type(8)));
typedef float f32x4  __attribute__((ext_vector_type(4)));
typedef _Float16 f16;
typedef unsigned long long u64;

__device__ __forceinline__ float bf2f(unsigned short u) {
  union { unsigned u32; float f; } v; v.u32 = ((unsigned)u) << 16; return v.f;
}
__device__ __forceinline__ unsigned short f2bf(float f) {
  union { float f; unsigned u; } v; v.f = f;
  unsigned r = (v.u + 0x7FFFu + ((v.u >> 16) & 1u)) >> 16;   // RNE
  return (unsigned short)r;
}

// ---- init: seed pub pairs; detect input dtype (bf16 vs fp32) --------------
// parity-0 slots = {counter 0, h=0.0} (valid for step 0), parity-1 = {-1,0}.
__global__ void init_k(const unsigned short* __restrict__ ctx,
                       u64* __restrict__ pub, int* __restrict__ df) {
  int i = blockIdx.x * 256 + threadIdx.x;
  if (i < 2 * 2 * 600) {
    int par = (i / 600) & 1;                   // layout [d][par][600]
    pub[i] = par ? 0x00000000FFFFFFFFull : 0ull;
  }
  if (blockIdx.x == 0 && threadIdx.x == 0) {
    int bad = 0;
    for (int k = 0; k < 512; ++k) {
      unsigned e = (ctx[2 * k] >> 7) & 0xFFu;
      bad += (e >= 0xF0u) | (e < 0x10u);
    }
    df[0] = (bad > 0) ? 1 : 0;
  }
}

// ---- embed + concat -> X bf16 [16384][512] --------------------------------
__global__ void embed_k(const unsigned short* __restrict__ ctx,
                        const int* __restrict__ tags,
                        const unsigned short* __restrict__ temb,
                        unsigned short* __restrict__ x,
                        const int* __restrict__ df) {
  const int fp32 = df[0];
  int idx = blockIdx.x * 256 + threadIdx.x;
  int row = idx >> 9, j = idx & 511;
  unsigned short v;
  if (fp32) {
    const float* ctxF  = (const float*)ctx;
    const float* tembF = (const float*)temb;
    v = (j < 3) ? f2bf(tembF[tags[row] * 3 + j]) : f2bf(ctxF[row * 509 + (j - 3)]);
  } else {
    v = (j < 3) ? temb[tags[row] * 3 + j] : ctx[row * 509 + (j - 3)];
  }
  x[idx] = v;
}

// ---- W_ih -> bf16 copy (no-op copy in bf16 mode) --------------------------
__global__ void wcast_k(const unsigned short* __restrict__ wih,
                        unsigned short* __restrict__ wb,
                        const int* __restrict__ df) {
  const int fp32 = df[0];
  int i = blockIdx.x * 256 + threadIdx.x;            // 1800*512 total
  wb[i] = fp32 ? f2bf(((const float*)wih)[i]) : wih[i];
}

// ---- GEMM: gx[16384][1800] = X @ W_ih^T + b_ih (fp16 out) -----------------
__global__ __launch_bounds__(256) void gemm_k(const unsigned short* __restrict__ X,
                                              const unsigned short* __restrict__ Wb,
                                              const unsigned short* __restrict__ bih,
                                              f16* __restrict__ gx,
                                              const int* __restrict__ df) {
  const int fp32 = df[0];
  const int lane = threadIdx.x & 63;
  const int wv   = threadIdx.x >> 6;
  const int mt   = blockIdx.y * 4 + wv;              // 0..1023
  const int nt   = blockIdx.x;                       // 0..112
  const int mrow = mt * 16 + (lane & 15);
  const int ncol = nt * 16 + (lane & 15);
  const int koff = (lane >> 4) * 8;                  // A[m][k=quad*8+j]
  const int nclamp = (ncol < TH3) ? ncol : (TH3 - 1);

  const bf16x8* ap = (const bf16x8*)(X  + (size_t)mrow   * KDIM + koff);
  const bf16x8* bp = (const bf16x8*)(Wb + (size_t)nclamp * KDIM + koff);

  f32x4 acc = {0.f, 0.f, 0.f, 0.f};
  #pragma unroll
  for (int kc = 0; kc < 16; ++kc) {
    bf16x8 av = ap[kc * 4];
    bf16x8 bv = bp[kc * 4];
    acc = __builtin_amdgcn_mfma_f32_16x16x32_bf16(av, bv, acc, 0, 0, 0);
  }
  if (ncol < TH3) {
    const float bias = fp32 ? ((const float*)bih)[ncol] : bf2f(bih[ncol]);
    const int r0 = mt * 16 + (lane >> 4) * 4;        // C/D: col=lane&15, row=quad*4+reg
    #pragma unroll
    for (int i = 0; i < 4; ++i)
      gx[(size_t)(r0 + i) * TH3 + ncol] = (f16)(acc[i] + bias);
  }
}

// ---- persistent bidirectional GRU recurrence ------------------------------
// 150 WGs (d = bid&1, w = bid>>1). WG owns h[8w..8w+8) of its direction.
// W_hh slice (24 rows x 600, fp32) in VGPRs. Publication: pub[d][par][p]
// (p = element index 0..599) is a u64 {counter | f32bits<<32}; at step t a
// reader polls parity t&1 for counter == t. Counters in a slot only take
// values == t (mod 2) and can never exceed the slowest reader's t+1, so
// "== t" is exact. 8-byte aligned atomic load/store (dwordx2) is untorn.
__global__ __launch_bounds__(256, 1) void gru_rec(const unsigned short* __restrict__ Whh,
                                                  const unsigned short* __restrict__ bhh,
                                                  const f16* __restrict__ gx,
                                                  u64* __restrict__ pub,      // [2][2][600]
                                                  void* __restrict__ outv,
                                                  const int* __restrict__ df) {
  const int fp32 = df[0];
  const int tid = threadIdx.x;
  const int d   = blockIdx.x & 1;
  const int w   = blockIdx.x >> 1;

  __shared__ __align__(16) float hlds[HPAD];
  __shared__ float ghl[24];

  if (tid < HPAD - HDIM) hlds[HDIM + tid] = 0.f;

  const int r = tid >> 3;            // 0..31 (24 used)
  const int c = tid & 7;
  const bool dot_t = (tid < 192);
  f32x4 wvr[19];
  if (dot_t) {
    const int g = r >> 3, e = r & 7;
    const int row = g * HDIM + w * EPW + e;
    if (fp32) {
      const float* wp = ((const float*)Whh) + (size_t)row * HDIM + c * CH;
      #pragma unroll
      for (int q = 0; q < 19; ++q) {
        const int kb = c * CH + q * 4;
        f32x4 v;
        if (kb + 3 < HDIM) {
          v = *(const f32x4*)(wp + q * 4);
        } else {
          #pragma unroll
          for (int j = 0; j < 4; ++j)
            v[j] = (kb + j < HDIM) ? wp[q * 4 + j] : 0.f;
        }
        wvr[q] = v;
      }
    } else {
      const unsigned short* wp = Whh + (size_t)row * HDIM + c * CH;
      #pragma unroll
      for (int q = 0; q < 19; ++q) {
        const int kb = c * CH + q * 4;
        f32x4 v;
        if (kb + 3 < HDIM) {
          ushort4 u = *(const ushort4*)(wp + q * 4);
          v[0] = bf2f(u.x); v[1] = bf2f(u.y); v[2] = bf2f(u.z); v[3] = bf2f(u.w);
        } else {
          #pragma unroll
          for (int j = 0; j < 4; ++j)
            v[j] = (kb + j < HDIM) ? bf2f(wp[q * 4 + j]) : 0.f;
        }
        wvr[q] = v;
      }
    }
  }

  float bhr = 0.f, bhz = 0.f, bhn = 0.f;
  if (tid < EPW) {
    const int i = w * EPW + tid;
    if (fp32) {
      const float* bF = (const float*)bhh;
      bhr = bF[i]; bhz = bF[HDIM + i]; bhn = bF[2 * HDIM + i];
    } else {
      bhr = bf2f(bhh[i]); bhz = bf2f(bhh[HDIM + i]); bhn = bf2f(bhh[2 * HDIM + i]);
    }
  }

  float hold = 0.f;                  // owner's own h element, carried in-reg

  for (int t = 0; t < NSTEP; ++t) {
    // prefetch this step's gx (independent of h; overlaps poll latency)
    float gxr = 0.f, gxz = 0.f, gxn = 0.f;
    if (tid < EPW) {
      const int rw = (d == 0) ? t : (((t >> 10) << 10) + (1023 - (t & 1023)));
      const f16* p = gx + (size_t)rw * TH3 + w * EPW + tid;
      gxr = (float)p[0]; gxz = (float)p[HDIM]; gxn = (float)p[2 * HDIM];
    }
    // poll+stash: gather h_t from the 600 self-validating pairs into LDS
    {
      const u64* base = pub + (size_t)(d * 2 + (t & 1)) * 600;
      #pragma unroll
      for (int j = 0; j < 3; ++j) {
        const int p = tid + 256 * j;
        if (p < HDIM) {
          u64 v = __hip_atomic_load(base + p, __ATOMIC_RELAXED, __HIP_MEMORY_SCOPE_AGENT);
          while ((int)(unsigned)v != t) {
            __builtin_amdgcn_s_sleep(1);
            v = __hip_atomic_load(base + p, __ATOMIC_RELAXED, __HIP_MEMORY_SCOPE_AGENT);
          }
          union { unsigned u; float f; } cv; cv.u = (unsigned)(v >> 32);
          hlds[p] = cv.f;
        }
      }
    }
    __syncthreads();
    // 24 row-dots of length 600 (W in regs, h in LDS, 8-way broadcast)
    if (dot_t) {
      float acc = 0.f;
      const float* hp = hlds + c * CH;
      #pragma unroll
      for (int q = 0; q < 19; ++q) {
        f32x4 h4 = *(const f32x4*)(hp + 4 * q);
        acc += wvr[q][0] * h4[0] + wvr[q][1] * h4[1]
             + wvr[q][2] * h4[2] + wvr[q][3] * h4[3];
      }
      acc += __shfl_xor(acc, 1);
      acc += __shfl_xor(acc, 2);
      acc += __shfl_xor(acc, 4);
      if (c == 0) ghl[r] = acc;
    }
    __syncthreads();
    // gates + state update (fp32); publish h_{t+1} immediately (no drain)
    if (tid < EPW) {
      const float rr  = 1.f / (1.f + __expf(-(gxr + ghl[tid] + bhr)));
      const float zz  = 1.f / (1.f + __expf(-(gxz + ghl[8 + tid] + bhz)));
      const float pre = gxn + rr * (ghl[16 + tid] + bhn);
      const float nn  = 1.f - 2.f / (1.f + __expf(2.f * pre));   // tanh(pre)
      const float hn  = nn + zz * (hold - nn);
      hold = hn;
      union { float f; unsigned u; } hv; hv.f = hn;
      const u64 pk = ((u64)hv.u << 32) | (unsigned)(t + 1);
      u64* dst = pub + (size_t)(d * 2 + ((t + 1) & 1)) * 600 + w * EPW + tid;
      __hip_atomic_store(dst, pk, __ATOMIC_RELAXED, __HIP_MEMORY_SCOPE_AGENT);
      if (t == NSTEP - 1) {
        const int o = d * HDIM + w * EPW + tid;
        if (fp32) ((float*)outv)[o] = hn;
        else      ((unsigned short*)outv)[o] = f2bf(hn);
      }
    }
    // NOTE: no barrier here. Fast threads may enter step t+1's poll, but all
    // hlds reads of step t happened before the 2nd barrier, and ghl reads by
    // owners complete before those owners join step t+1's 1st barrier.
  }
}

extern "C" void kernel_launch(void* const* d_in, const int* in_sizes, int n_in,
                              void* d_out, int out_size, void* d_ws, size_t ws_size,
                              hipStream_t stream) {
  const unsigned short* ctx  = (const unsigned short*)d_in[0];
  const int*            tags = (const int*)d_in[1];
  const unsigned short* temb = (const unsigned short*)d_in[2];
  const unsigned short* wih  = (const unsigned short*)d_in[3];
  const unsigned short* whh  = (const unsigned short*)d_in[4];
  const unsigned short* bih  = (const unsigned short*)d_in[5];
  const unsigned short* bhh  = (const unsigned short*)d_in[6];

  char* ws = (char*)d_ws;
  unsigned short* X  = (unsigned short*)ws;
  f16*            GX = (f16*)(ws + OFF_GX);
  u64*            PB = (u64*)  (ws + OFF_PB);
  int*            DF = (int*)  (ws + OFF_DF);
  unsigned short* WB = (unsigned short*)(ws + OFF_WB);

  init_k <<<32, 256, 0, stream>>>(ctx, PB, DF);
  embed_k<<<(NROWS * KDIM) / 256, 256, 0, stream>>>(ctx, tags, temb, X, DF);
  wcast_k<<<(TH3 * KDIM) / 256, 256, 0, stream>>>(wih, WB, DF);
  gemm_k <<<dim3(113, 256), 256, 0, stream>>>(X, WB, bih, GX, DF);
  gru_rec<<<2 * NW, 256, 0, stream>>>(whh, bhh, GX, PB, d_out, DF);
}

// Round 6
// 30044.153 us; speedup vs baseline: 3.9049x; 1.2491x over previous
//
#include <hip/hip_runtime.h>

// Problem: B=16, S=1024, C=509 -> IN=512, H=600, bidirectional GRU, one serial
// hidden state over all 16384 steps per direction.
//
// R5: fused data+flag publication (u64 {ctr, f32bits} per h element, parity
// double-buffered, monotonic) -> 2.28 us/step best-case.
// R6: (a) busy-poll without s_sleep — R5 showed a bimodal 37/67 ms profile
// with identical counters, i.e. uniform time dilation = DPM downclock while
// ~95% of waves sleep; busy issue keeps clocks pinned. (b) joint spin: each
// thread keeps all its pending slots in flight per sweep instead of fully
// draining slot 0 before looking at slot 1/2.
//
// Workspace layout (total ~74.0 MiB):
//   X   @ 0           : 16384*512*2  = 16,777,216
//   GX  @ 16,777,216  : 16384*1800*2 = 58,982,400 (fp16)   end 75,759,616
//   PUB @ 75,776,000  : 2dir*2par*600*8B = 19,200 (h+counter pairs)
//   DF  @ 75,795,200  : 256 (dtype flag)
//   WB  @ 75,795,456  : 1800*512*2 = 1,843,200 (W_ih bf16)  end 77,638,656

#define HDIM   600
#define TH3    1800
#define NROWS  16384
#define KDIM   512
#define NW     75
#define EPW    8
#define NSTEP  16384
#define CH     76
#define HPAD   608

#define OFF_GX 16777216ull
#define OFF_PB 75776000ull
#define OFF_DF 75795200ull
#define OFF_WB 75795456ull

typedef short bf16x8 __attribute__((ext_vector_type(8)));
typedef float f32x4  __attribute__((ext_vector_type(4)));
typedef _Float16 f16;
typedef unsigned long long u64;

__device__ __forceinline__ float bf2f(unsigned short u) {
  union { unsigned u32; float f; } v; v.u32 = ((unsigned)u) << 16; return v.f;
}
__device__ __forceinline__ unsigned short f2bf(float f) {
  union { float f; unsigned u; } v; v.f = f;
  unsigned r = (v.u + 0x7FFFu + ((v.u >> 16) & 1u)) >> 16;   // RNE
  return (unsigned short)r;
}

// ---- init: seed pub pairs; detect input dtype (bf16 vs fp32) --------------
// parity-0 slots = {counter 0, h=0.0} (valid for step 0), parity-1 = {-1,0}.
__global__ void init_k(const unsigned short* __restrict__ ctx,
                       u64* __restrict__ pub, int* __restrict__ df) {
  int i = blockIdx.x * 256 + threadIdx.x;
  if (i < 2 * 2 * 600) {
    int par = (i / 600) & 1;                   // layout [d][par][600]
    pub[i] = par ? 0x00000000FFFFFFFFull : 0ull;
  }
  if (blockIdx.x == 0 && threadIdx.x == 0) {
    int bad = 0;
    for (int k = 0; k < 512; ++k) {
      unsigned e = (ctx[2 * k] >> 7) & 0xFFu;
      bad += (e >= 0xF0u) | (e < 0x10u);
    }
    df[0] = (bad > 0) ? 1 : 0;
  }
}

// ---- embed + concat -> X bf16 [16384][512] --------------------------------
__global__ void embed_k(const unsigned short* __restrict__ ctx,
                        const int* __restrict__ tags,
                        const unsigned short* __restrict__ temb,
                        unsigned short* __restrict__ x,
                        const int* __restrict__ df) {
  const int fp32 = df[0];
  int idx = blockIdx.x * 256 + threadIdx.x;
  int row = idx >> 9, j = idx & 511;
  unsigned short v;
  if (fp32) {
    const float* ctxF  = (const float*)ctx;
    const float* tembF = (const float*)temb;
    v = (j < 3) ? f2bf(tembF[tags[row] * 3 + j]) : f2bf(ctxF[row * 509 + (j - 3)]);
  } else {
    v = (j < 3) ? temb[tags[row] * 3 + j] : ctx[row * 509 + (j - 3)];
  }
  x[idx] = v;
}

// ---- W_ih -> bf16 copy (no-op copy in bf16 mode) --------------------------
__global__ void wcast_k(const unsigned short* __restrict__ wih,
                        unsigned short* __restrict__ wb,
                        const int* __restrict__ df) {
  const int fp32 = df[0];
  int i = blockIdx.x * 256 + threadIdx.x;            // 1800*512 total
  wb[i] = fp32 ? f2bf(((const float*)wih)[i]) : wih[i];
}

// ---- GEMM: gx[16384][1800] = X @ W_ih^T + b_ih (fp16 out) -----------------
__global__ __launch_bounds__(256) void gemm_k(const unsigned short* __restrict__ X,
                                              const unsigned short* __restrict__ Wb,
                                              const unsigned short* __restrict__ bih,
                                              f16* __restrict__ gx,
                                              const int* __restrict__ df) {
  const int fp32 = df[0];
  const int lane = threadIdx.x & 63;
  const int wv   = threadIdx.x >> 6;
  const int mt   = blockIdx.y * 4 + wv;              // 0..1023
  const int nt   = blockIdx.x;                       // 0..112
  const int mrow = mt * 16 + (lane & 15);
  const int ncol = nt * 16 + (lane & 15);
  const int koff = (lane >> 4) * 8;                  // A[m][k=quad*8+j]
  const int nclamp = (ncol < TH3) ? ncol : (TH3 - 1);

  const bf16x8* ap = (const bf16x8*)(X  + (size_t)mrow   * KDIM + koff);
  const bf16x8* bp = (const bf16x8*)(Wb + (size_t)nclamp * KDIM + koff);

  f32x4 acc = {0.f, 0.f, 0.f, 0.f};
  #pragma unroll
  for (int kc = 0; kc < 16; ++kc) {
    bf16x8 av = ap[kc * 4];
    bf16x8 bv = bp[kc * 4];
    acc = __builtin_amdgcn_mfma_f32_16x16x32_bf16(av, bv, acc, 0, 0, 0);
  }
  if (ncol < TH3) {
    const float bias = fp32 ? ((const float*)bih)[ncol] : bf2f(bih[ncol]);
    const int r0 = mt * 16 + (lane >> 4) * 4;        // C/D: col=lane&15, row=quad*4+reg
    #pragma unroll
    for (int i = 0; i < 4; ++i)
      gx[(size_t)(r0 + i) * TH3 + ncol] = (f16)(acc[i] + bias);
  }
}

// ---- persistent bidirectional GRU recurrence ------------------------------
// 150 WGs (d = bid&1, w = bid>>1). WG owns h[8w..8w+8) of its direction.
// W_hh slice (24 rows x 600, fp32) in VGPRs. Publication: pub[d][par][p]
// (p = element index 0..599) is a u64 {counter | f32bits<<32}; at step t a
// reader polls parity t&1 for counter == t. A slot can only be overwritten
// with t+2 after every WG has finished its step-t gather (data dependency
// through the counters), so "== t" is exact; 8B-aligned atomics are untorn.
__global__ __launch_bounds__(256, 1) void gru_rec(const unsigned short* __restrict__ Whh,
                                                  const unsigned short* __restrict__ bhh,
                                                  const f16* __restrict__ gx,
                                                  u64* __restrict__ pub,      // [2][2][600]
                                                  void* __restrict__ outv,
                                                  const int* __restrict__ df) {
  const int fp32 = df[0];
  const int tid = threadIdx.x;
  const int d   = blockIdx.x & 1;
  const int w   = blockIdx.x >> 1;

  __shared__ __align__(16) float hlds[HPAD];
  __shared__ float ghl[24];

  if (tid < HPAD - HDIM) hlds[HDIM + tid] = 0.f;

  const int r = tid >> 3;            // 0..31 (24 used)
  const int c = tid & 7;
  const bool dot_t = (tid < 192);
  f32x4 wvr[19];
  if (dot_t) {
    const int g = r >> 3, e = r & 7;
    const int row = g * HDIM + w * EPW + e;
    if (fp32) {
      const float* wp = ((const float*)Whh) + (size_t)row * HDIM + c * CH;
      #pragma unroll
      for (int q = 0; q < 19; ++q) {
        const int kb = c * CH + q * 4;
        f32x4 v;
        if (kb + 3 < HDIM) {
          v = *(const f32x4*)(wp + q * 4);
        } else {
          #pragma unroll
          for (int j = 0; j < 4; ++j)
            v[j] = (kb + j < HDIM) ? wp[q * 4 + j] : 0.f;
        }
        wvr[q] = v;
      }
    } else {
      const unsigned short* wp = Whh + (size_t)row * HDIM + c * CH;
      #pragma unroll
      for (int q = 0; q < 19; ++q) {
        const int kb = c * CH + q * 4;
        f32x4 v;
        if (kb + 3 < HDIM) {
          ushort4 u = *(const ushort4*)(wp + q * 4);
          v[0] = bf2f(u.x); v[1] = bf2f(u.y); v[2] = bf2f(u.z); v[3] = bf2f(u.w);
        } else {
          #pragma unroll
          for (int j = 0; j < 4; ++j)
            v[j] = (kb + j < HDIM) ? bf2f(wp[q * 4 + j]) : 0.f;
        }
        wvr[q] = v;
      }
    }
  }

  float bhr = 0.f, bhz = 0.f, bhn = 0.f;
  if (tid < EPW) {
    const int i = w * EPW + tid;
    if (fp32) {
      const float* bF = (const float*)bhh;
      bhr = bF[i]; bhz = bF[HDIM + i]; bhn = bF[2 * HDIM + i];
    } else {
      bhr = bf2f(bhh[i]); bhz = bf2f(bhh[HDIM + i]); bhn = bf2f(bhh[2 * HDIM + i]);
    }
  }

  float hold = 0.f;                  // owner's own h element, carried in-reg

  for (int t = 0; t < NSTEP; ++t) {
    // prefetch this step's gx (independent of h; overlaps poll latency)
    float gxr = 0.f, gxz = 0.f, gxn = 0.f;
    if (tid < EPW) {
      const int rw = (d == 0) ? t : (((t >> 10) << 10) + (1023 - (t & 1023)));
      const f16* p = gx + (size_t)rw * TH3 + w * EPW + tid;
      gxr = (float)p[0]; gxz = (float)p[HDIM]; gxn = (float)p[2 * HDIM];
    }
    // poll+stash: gather h_t from the 600 self-validating pairs into LDS.
    // Busy-poll (no s_sleep -> DPM keeps clocks up); all of a thread's
    // pending slots stay in flight each sweep (joint spin, no serial tail).
    {
      const u64* base = pub + (size_t)(d * 2 + (t & 1)) * 600;
      const unsigned ut = (unsigned)t;
      const int p1 = tid + 256, p2 = tid + 512;
      bool d0 = false, d1 = (p1 >= HDIM), d2 = (p2 >= HDIM);
      while (!(d0 & d1 & d2)) {
        u64 a0 = 0, a1 = 0, a2 = 0;
        if (!d0) a0 = __hip_atomic_load(base + tid, __ATOMIC_RELAXED, __HIP_MEMORY_SCOPE_AGENT);
        if (!d1) a1 = __hip_atomic_load(base + p1,  __ATOMIC_RELAXED, __HIP_MEMORY_SCOPE_AGENT);
        if (!d2) a2 = __hip_atomic_load(base + p2,  __ATOMIC_RELAXED, __HIP_MEMORY_SCOPE_AGENT);
        if (!d0 && (unsigned)a0 == ut) {
          union { unsigned u; float f; } cv; cv.u = (unsigned)(a0 >> 32);
          hlds[tid] = cv.f; d0 = true;
        }
        if (!d1 && (unsigned)a1 == ut) {
          union { unsigned u; float f; } cv; cv.u = (unsigned)(a1 >> 32);
          hlds[p1] = cv.f; d1 = true;
        }
        if (!d2 && (unsigned)a2 == ut) {
          union { unsigned u; float f; } cv; cv.u = (unsigned)(a2 >> 32);
          hlds[p2] = cv.f; d2 = true;
        }
      }
    }
    __syncthreads();
    // 24 row-dots of length 600 (W in regs, h in LDS, 8-way broadcast)
    if (dot_t) {
      float acc = 0.f;
      const float* hp = hlds + c * CH;
      #pragma unroll
      for (int q = 0; q < 19; ++q) {
        f32x4 h4 = *(const f32x4*)(hp + 4 * q);
        acc += wvr[q][0] * h4[0] + wvr[q][1] * h4[1]
             + wvr[q][2] * h4[2] + wvr[q][3] * h4[3];
      }
      acc += __shfl_xor(acc, 1);
      acc += __shfl_xor(acc, 2);
      acc += __shfl_xor(acc, 4);
      if (c == 0) ghl[r] = acc;
    }
    __syncthreads();
    // gates + state update (fp32); publish h_{t+1} immediately (no drain)
    if (tid < EPW) {
      const float rr  = 1.f / (1.f + __expf(-(gxr + ghl[tid] + bhr)));
      const float zz  = 1.f / (1.f + __expf(-(gxz + ghl[8 + tid] + bhz)));
      const float pre = gxn + rr * (ghl[16 + tid] + bhn);
      const float nn  = 1.f - 2.f / (1.f + __expf(2.f * pre));   // tanh(pre)
      const float hn  = nn + zz * (hold - nn);
      hold = hn;
      union { float f; unsigned u; } hv; hv.f = hn;
      const u64 pk = ((u64)hv.u << 32) | (unsigned)(t + 1);
      u64* dst = pub + (size_t)(d * 2 + ((t + 1) & 1)) * 600 + w * EPW + tid;
      __hip_atomic_store(dst, pk, __ATOMIC_RELAXED, __HIP_MEMORY_SCOPE_AGENT);
      if (t == NSTEP - 1) {
        const int o = d * HDIM + w * EPW + tid;
        if (fp32) ((float*)outv)[o] = hn;
        else      ((unsigned short*)outv)[o] = f2bf(hn);
      }
    }
    // NOTE: no barrier here. Fast threads may enter step t+1's poll, but all
    // hlds reads of step t happened before the 2nd barrier, and ghl reads by
    // owners complete before those owners join step t+1's 1st barrier.
  }
}

extern "C" void kernel_launch(void* const* d_in, const int* in_sizes, int n_in,
                              void* d_out, int out_size, void* d_ws, size_t ws_size,
                              hipStream_t stream) {
  const unsigned short* ctx  = (const unsigned short*)d_in[0];
  const int*            tags = (const int*)d_in[1];
  const unsigned short* temb = (const unsigned short*)d_in[2];
  const unsigned short* wih  = (const unsigned short*)d_in[3];
  const unsigned short* whh  = (const unsigned short*)d_in[4];
  const unsigned short* bih  = (const unsigned short*)d_in[5];
  const unsigned short* bhh  = (const unsigned short*)d_in[6];

  char* ws = (char*)d_ws;
  unsigned short* X  = (unsigned short*)ws;
  f16*            GX = (f16*)(ws + OFF_GX);
  u64*            PB = (u64*)  (ws + OFF_PB);
  int*            DF = (int*)  (ws + OFF_DF);
  unsigned short* WB = (unsigned short*)(ws + OFF_WB);

  init_k <<<32, 256, 0, stream>>>(ctx, PB, DF);
  embed_k<<<(NROWS * KDIM) / 256, 256, 0, stream>>>(ctx, tags, temb, X, DF);
  wcast_k<<<(TH3 * KDIM) / 256, 256, 0, stream>>>(wih, WB, DF);
  gemm_k <<<dim3(113, 256), 256, 0, stream>>>(X, WB, bih, GX, DF);
  gru_rec<<<2 * NW, 256, 0, stream>>>(whh, bhh, GX, PB, d_out, DF);
}